// Round 6
// baseline (486.768 us; speedup 1.0000x reference)
//
#include <hip/hip_runtime.h>

#define B_   8
#define S_   2048
#define H_   768
#define K_   128
#define C_   256
#define SH_  2052              // S + 4 halo rows (2 each side)
#define MTOK (B_*S_)           // 16384 tokens

typedef __attribute__((ext_vector_type(8))) short short8;
typedef __attribute__((ext_vector_type(4))) float f32x4;

typedef __attribute__((address_space(1))) const void gvoid;
typedef __attribute__((address_space(3))) void lvoid;

__device__ __forceinline__ void gload16(const void* g, void* l) {
    __builtin_amdgcn_global_load_lds((gvoid*)g, (lvoid*)l, 16, 0, 0);
}

__device__ __forceinline__ ushort f2b(float f) {
    union { float f; unsigned u; } v; v.f = f;
    unsigned r = v.u + 0x7fffu + ((v.u >> 16) & 1u);   // RNE
    return (ushort)(r >> 16);
}
__device__ __forceinline__ float b2f(ushort u) {
    union { unsigned u; float f; } v; v.u = ((unsigned)u) << 16;
    return v.f;
}
__device__ __forceinline__ float fast_tanh(float x) {
    float e = __expf(2.f * x);
    return 1.f - 2.f / (e + 1.f);
}

// ---------------- small prep kernels ----------------

__global__ __launch_bounds__(512) void k_maxlen(const float* __restrict__ mask, int* Lp) {
    __shared__ float sh[8];
    const int tid = threadIdx.x;
    float mx = 0.f;
    for (int b = 0; b < B_; ++b) {
        const float4 v = ((const float4*)(mask + b * S_))[tid];
        float s = v.x + v.y + v.z + v.w;
#pragma unroll
        for (int off = 32; off; off >>= 1) s += __shfl_xor(s, off);
        if ((tid & 63) == 0) sh[tid >> 6] = s;
        __syncthreads();
        if (tid == 0) {
            float t = 0.f;
#pragma unroll
            for (int q = 0; q < 8; ++q) t += sh[q];
            mx = fmaxf(mx, t);
        }
        __syncthreads();
    }
    if (tid == 0) *Lp = (int)mx;
}

// build halo'd bf16 copy of representation (vectorized x4)
__global__ void k_build_xh(const float* __restrict__ rep, ushort* __restrict__ xh) {
    int i = blockIdx.x * blockDim.x + threadIdx.x;
    const int stride = gridDim.x * blockDim.x;
    const int n4 = B_ * SH_ * H_ / 4;
    for (; i < n4; i += stride) {
        const int idx = i * 4;
        const int h = idx % H_;
        const int rs = idx / H_;
        const int s = rs % SH_;
        const int b = rs / SH_;
        ushort4 o; o.x = 0; o.y = 0; o.z = 0; o.w = 0;
        if (s >= 2 && s < S_ + 2) {
            const float4 v = *(const float4*)(rep + ((size_t)b * S_ + (s - 2)) * H_ + h);
            o.x = f2b(v.x); o.y = f2b(v.y); o.z = f2b(v.z); o.w = f2b(v.w);
        }
        *(ushort4*)(xh + idx) = o;
    }
}

// fused weight conversions: 11 entries in one launch
struct CvtE { const float* src; ushort* dst; int n; int kh; };  // kh=0: copy, else [KH][C]->[C][KH]
struct CvtAll { CvtE e[11]; };

__global__ void k_cvt_all(CvtAll a) {
    const CvtE e = a.e[blockIdx.y];
    int i = blockIdx.x * blockDim.x + threadIdx.x;
    const int stride = gridDim.x * blockDim.x;
    for (; i < e.n; i += stride) {
        if (e.kh) {
            const int c = i / e.kh;
            const int r = i - c * e.kh;
            e.dst[i] = f2b(e.src[r * C_ + c]);
        } else {
            e.dst[i] = f2b(e.src[i]);
        }
    }
}

// ---------------- gemm_big: 256x256x64, 8 waves (2x4), wave tile 128x64 ----------------
// Double-buffered 128 KB LDS. Per tile: vmcnt(8) -> barrier -> frag reads ->
// MFMA (M-low) -> A-high reads -> lgkmcnt(0) -> barrier2 (all reads done) ->
// stage(t+2) into drained buffer -> MFMA (M-high). Counted vmcnt; never 0 mid-loop.
// CONV mode: 4 branch-sets {k5a(taps0-2), k3, k5b(taps3-4), k1}; k5 partials in f32.

struct GBP {
    const ushort* A;     // linear A / conv Xh (halo'd)
    const ushort* W;     // linear weight
    const ushort* w1; const ushort* w3; const ushort* w5;   // conv weights [256][K]
    int Ktot;            // linear only
    int lda;
    ushort* outB; int ldoB;   // linear bf16 out
    float*  outF; int ldoF;   // linear f32 out
    int act;
    ushort* convB;            // conv bf16 out [MTOK][768]
    float* PA; float* PB;     // conv k5 f32 partials [MTOK][256]
};

template<bool CONV>
__global__ __launch_bounds__(512) void gemm_big(GBP p) {
    __shared__ __align__(16) ushort lds[2][4096 * 8];   // per buf: A 2048 segs, B 2048 segs

    const int tid = threadIdx.x;
    const int w = tid >> 6, lane = tid & 63;
    const int l15 = lane & 15, lk = lane >> 4;
    const int wr = w >> 2, wc = w & 3;        // 2 x 4 wave grid, wave tile 128x64
    const int axor = l15 & 7;

    int m_base, n_base = 0, nt, kbase = 0, abase = 0, set = 0, wstride, lda = p.lda;
    const ushort* Wt;
    if (CONV) {
        set = blockIdx.x >> 6;
        m_base = (blockIdx.x & 63) * 256;
        if (set == 0)      { Wt = p.w5; wstride = 3840; kbase = 0;    abase = 0; nt = 36; }  // k5a
        else if (set == 1) { Wt = p.w3; wstride = 2304; kbase = 0;    abase = 1; nt = 36; }  // k3
        else if (set == 2) { Wt = p.w5; wstride = 3840; kbase = 2304; abase = 3; nt = 24; }  // k5b
        else               { Wt = p.w1; wstride = 768;  kbase = 0;    abase = 2; nt = 12; }  // k1
    } else {
        m_base = blockIdx.x * 256;
        n_base = blockIdx.y * 256;
        Wt = p.W; wstride = p.Ktot; nt = p.Ktot >> 6;
    }
    const int bb = m_base >> 11;
    const int arow0 = CONV ? (m_base + 4 * bb + abase) : m_base;

    auto stage = [&](int kt, int bufi) {
        int klocal = kt, taprow = 0;
        if (CONV) { taprow = kt / 12; klocal = kt - taprow * 12; }
        const int h0 = klocal << 6;                 // A: within-row col (per-tap wrap)
        const int wcol = kbase + (kt << 6);         // W: K-dim contiguous across taps (BUGFIX)
        ushort* Ab = &lds[bufi][0];
        ushort* Bb = &lds[bufi][2048 * 8];
#pragma unroll
        for (int q = 0; q < 4; ++q) {
            const int seg = q * 512 + tid;
            const int row = seg >> 3;
            const int s = (seg & 7) ^ (row & 7);
            gload16(p.A + (size_t)(arow0 + taprow + row) * lda + h0 + s * 8, Ab + seg * 8);
        }
#pragma unroll
        for (int q = 0; q < 4; ++q) {
            const int seg = q * 512 + tid;
            const int row = seg >> 3;
            const int s = (seg & 7) ^ (row & 7);
            const int wrow = (CONV ? 0 : n_base) + row;
            gload16(Wt + (size_t)wrow * wstride + wcol + s * 8, Bb + seg * 8);
        }
    };

    f32x4 acc[8][4] = {};

    stage(0, 0);
    stage(1, 1);

    for (int t = 0; t < nt; ++t) {
        const int cur = t & 1;
        const ushort* Ab = &lds[cur][0];
        const ushort* Bb = &lds[cur][2048 * 8];
        if (t + 1 < nt) asm volatile("s_waitcnt vmcnt(8)" ::: "memory");
        else            asm volatile("s_waitcnt vmcnt(0)" ::: "memory");
        __builtin_amdgcn_sched_barrier(0);
        asm volatile("s_barrier" ::: "memory");     // tile t resident; t-1 compute done everywhere
        __builtin_amdgcn_sched_barrier(0);

        short8 af[4][2], bf[4][2];
#pragma unroll
        for (int mi = 0; mi < 4; ++mi)
#pragma unroll
            for (int ks = 0; ks < 2; ++ks)
                af[mi][ks] = *(const short8*)(Ab + (wr * 128 + mi * 16 + l15) * 64 + ((((ks << 2) | lk) ^ axor) << 3));
#pragma unroll
        for (int ni = 0; ni < 4; ++ni)
#pragma unroll
            for (int ks = 0; ks < 2; ++ks)
                bf[ni][ks] = *(const short8*)(Bb + (wc * 64 + ni * 16 + l15) * 64 + ((((ks << 2) | lk) ^ axor) << 3));
        asm volatile("s_waitcnt lgkmcnt(0)" ::: "memory");
        __builtin_amdgcn_sched_barrier(0);
        __builtin_amdgcn_s_setprio(1);
#pragma unroll
        for (int mi = 0; mi < 4; ++mi)
#pragma unroll
            for (int ni = 0; ni < 4; ++ni) {
                acc[mi][ni] = __builtin_amdgcn_mfma_f32_16x16x32_bf16(af[mi][0], bf[ni][0], acc[mi][ni], 0, 0, 0);
                acc[mi][ni] = __builtin_amdgcn_mfma_f32_16x16x32_bf16(af[mi][1], bf[ni][1], acc[mi][ni], 0, 0, 0);
            }
        __builtin_amdgcn_s_setprio(0);
        __builtin_amdgcn_sched_barrier(0);
        // A-high frags (reuse registers)
#pragma unroll
        for (int mi = 0; mi < 4; ++mi)
#pragma unroll
            for (int ks = 0; ks < 2; ++ks)
                af[mi][ks] = *(const short8*)(Ab + (wr * 128 + (4 + mi) * 16 + l15) * 64 + ((((ks << 2) | lk) ^ axor) << 3));
        asm volatile("s_waitcnt lgkmcnt(0)" ::: "memory");
        __builtin_amdgcn_sched_barrier(0);
        asm volatile("s_barrier" ::: "memory");     // barrier2: all waves' reads of buf cur complete
        __builtin_amdgcn_sched_barrier(0);
        if (t + 2 < nt) stage(t + 2, cur);          // overwrite drained buffer; lands under MFMA
        __builtin_amdgcn_sched_barrier(0);
        __builtin_amdgcn_s_setprio(1);
#pragma unroll
        for (int mi = 0; mi < 4; ++mi)
#pragma unroll
            for (int ni = 0; ni < 4; ++ni) {
                acc[4 + mi][ni] = __builtin_amdgcn_mfma_f32_16x16x32_bf16(af[mi][0], bf[ni][0], acc[4 + mi][ni], 0, 0, 0);
                acc[4 + mi][ni] = __builtin_amdgcn_mfma_f32_16x16x32_bf16(af[mi][1], bf[ni][1], acc[4 + mi][ni], 0, 0, 0);
            }
        __builtin_amdgcn_s_setprio(0);
        __builtin_amdgcn_sched_barrier(0);
    }

#pragma unroll
    for (int fi = 0; fi < 8; ++fi)
#pragma unroll
        for (int ni = 0; ni < 4; ++ni)
#pragma unroll
            for (int jj = 0; jj < 4; ++jj) {
                const int r = m_base + wr * 128 + fi * 16 + 4 * lk + jj;
                const int c = wc * 64 + ni * 16 + l15;     // 0..255 local
                float v = acc[fi][ni][jj];
                if (!CONV) {
                    if (p.act) v = fast_tanh(v);
                    if (p.outF) p.outF[(size_t)r * p.ldoF + n_base + c] = v;
                    if (p.outB) p.outB[(size_t)r * p.ldoB + n_base + c] = f2b(v);
                } else {
                    if (set == 0)      p.PA[(size_t)r * 256 + c] = v;
                    else if (set == 2) p.PB[(size_t)r * 256 + c] = v;
                    else if (set == 1) p.convB[(size_t)r * H_ + 256 + c] = f2b(v);
                    else               p.convB[(size_t)r * H_ + c] = f2b(v);
                }
            }
}

// ---------------- small LDS-staged GEMM (m97 2-phase) for N=128 / K=128 cases ----------

struct GemmP {
    const ushort* A;
    const ushort* Wt;
    int Ktot;
    int lda;
    ushort* outB;
    int ldoB;
    int outB_halo;      // row' = r + 4*(r>>11) + 2
    float* outF;
    int ldoF;
    int act;
};

template<int BM, int BN>
__global__ __launch_bounds__(256) void gemm_lds(GemmP p) {
    constexpr int MF = BM / 32;
    constexpr int NF = BN / 32;
    __shared__ __align__(16) ushort As[BM * 64];
    __shared__ __align__(16) ushort Bs[BN * 64];
    const int tid = threadIdx.x;
    const int w = tid >> 6, lane = tid & 63;
    const int l15 = lane & 15, lk = lane >> 4;
    const int m_base = blockIdx.x * BM;
    const int n_base = blockIdx.y * BN;
    const int wr = w >> 1, wc = w & 1;
    f32x4 acc[MF][NF] = {};
    const int srow = lane >> 3;
    const int scol = (lane & 7) * 8;
    const int nk = p.Ktot >> 6;

    for (int kt = 0; kt < nk; ++kt) {
        const int kk = kt << 6;
#pragma unroll
        for (int q = 0; q < BM / 32; ++q) {
            const int r = w * (BM / 4) + q * 8;
            gload16(p.A + (size_t)(m_base + r + srow) * p.lda + kk + scol, As + r * 64);
        }
#pragma unroll
        for (int q = 0; q < BN / 32; ++q) {
            const int r = w * (BN / 4) + q * 8;
            gload16(p.Wt + (size_t)(n_base + r + srow) * p.Ktot + kk + scol, Bs + r * 64);
        }
        __syncthreads();
#pragma unroll
        for (int ks = 0; ks < 2; ++ks) {
            short8 af[MF], bfr[NF];
#pragma unroll
            for (int i = 0; i < MF; ++i)
                af[i] = *(const short8*)(As + (wr * (BM / 2) + i * 16 + l15) * 64 + ks * 32 + 8 * lk);
#pragma unroll
            for (int j = 0; j < NF; ++j)
                bfr[j] = *(const short8*)(Bs + (wc * (BN / 2) + j * 16 + l15) * 64 + ks * 32 + 8 * lk);
#pragma unroll
            for (int i = 0; i < MF; ++i)
#pragma unroll
                for (int j = 0; j < NF; ++j)
                    acc[i][j] = __builtin_amdgcn_mfma_f32_16x16x32_bf16(af[i], bfr[j], acc[i][j], 0, 0, 0);
        }
        __syncthreads();
    }

    const int bb4 = ((m_base >> 11) << 2) + 2;
#pragma unroll
    for (int i = 0; i < MF; ++i)
#pragma unroll
        for (int j = 0; j < NF; ++j)
#pragma unroll
            for (int jj = 0; jj < 4; ++jj) {
                const int r = m_base + wr * (BM / 2) + i * 16 + 4 * lk + jj;
                const int n = n_base + wc * (BN / 2) + j * 16 + l15;
                float v = acc[i][j][jj];
                if (p.act) v = fast_tanh(v);
                if (p.outF) p.outF[(size_t)r * p.ldoF + n] = v;
                if (p.outB) {
                    const int rr = p.outB_halo ? (r + bb4) : r;
                    p.outB[(size_t)rr * p.ldoB + n] = f2b(v);
                }
            }
}

// ------- LayerNorm(conv_out + residual) -> bf16; cols 512-767 come from f32 partials ----

__global__ __launch_bounds__(192) void k_ln(const ushort* __restrict__ conv,
                                            const float* __restrict__ PA,
                                            const float* __restrict__ PB,
                                            const float* __restrict__ rep,
                                            const float* __restrict__ gw,
                                            const float* __restrict__ bw,
                                            ushort* __restrict__ out) {
    const int row = blockIdx.x;
    const int tid = threadIdx.x;
    const int h = tid * 4;
    const float4 rv = *(const float4*)(rep + (size_t)row * H_ + h);
    float v[4];
    if (h < 512) {
        const ushort4 cv = *(const ushort4*)(conv + (size_t)row * H_ + h);
        v[0] = b2f(cv.x) + rv.x; v[1] = b2f(cv.y) + rv.y;
        v[2] = b2f(cv.z) + rv.z; v[3] = b2f(cv.w) + rv.w;
    } else {
        const float4 a = *(const float4*)(PA + (size_t)row * 256 + (h - 512));
        const float4 b = *(const float4*)(PB + (size_t)row * 256 + (h - 512));
        v[0] = a.x + b.x + rv.x; v[1] = a.y + b.y + rv.y;
        v[2] = a.z + b.z + rv.z; v[3] = a.w + b.w + rv.w;
    }
    float s1 = v[0] + v[1] + v[2] + v[3];
    float s2 = v[0]*v[0] + v[1]*v[1] + v[2]*v[2] + v[3]*v[3];
#pragma unroll
    for (int off = 32; off; off >>= 1) { s1 += __shfl_xor(s1, off); s2 += __shfl_xor(s2, off); }
    __shared__ float sh[6];
    const int wid = tid >> 6, lane = tid & 63;
    if (lane == 0) { sh[wid] = s1; sh[3 + wid] = s2; }
    __syncthreads();
    s1 = sh[0] + sh[1] + sh[2];
    s2 = sh[3] + sh[4] + sh[5];
    const float mu  = s1 * (1.f / H_);
    const float var = s2 * (1.f / H_) - mu * mu;
    const float rs  = rsqrtf(var + 1e-5f);
    const float4 gv = *(const float4*)(gw + h);
    const float4 bv = *(const float4*)(bw + h);
    ushort4 o;
    o.x = f2b((v[0] - mu) * rs * gv.x + bv.x);
    o.y = f2b((v[1] - mu) * rs * gv.y + bv.y);
    o.z = f2b((v[2] - mu) * rs * gv.z + bv.z);
    o.w = f2b((v[3] - mu) * rs * gv.w + bv.w);
    *(ushort4*)(out + (size_t)row * H_ + h) = o;
}

// -------- merge decoder k5 partials: bufB[:,512:768] = bf16(PA+PB) --------

__global__ void k_merge(const float* __restrict__ PA, const float* __restrict__ PB,
                        ushort* __restrict__ out) {
    int i = blockIdx.x * blockDim.x + threadIdx.x;
    const int stride = gridDim.x * blockDim.x;
    const int n4 = MTOK * 256 / 4;
    for (; i < n4; i += stride) {
        const int idx = i * 4;
        const int row = idx >> 8;
        const int c = idx & 255;
        const float4 a = *(const float4*)(PA + idx);
        const float4 b = *(const float4*)(PB + idx);
        ushort4 o;
        o.x = f2b(a.x + b.x); o.y = f2b(a.y + b.y);
        o.z = f2b(a.z + b.z); o.w = f2b(a.w + b.w);
        *(ushort4*)(out + (size_t)row * H_ + 512 + c) = o;
    }
}

// ---------------- row-normalize location -> bf16 ----------------

__global__ __launch_bounds__(256) void k_normed(const float* __restrict__ loc, ushort* __restrict__ out) {
    const int wid = threadIdx.x >> 6, lane = threadIdx.x & 63;
    const int row = blockIdx.x * 4 + wid;
    const float* lp = loc + (size_t)row * K_;
    const float x0 = lp[lane], x1 = lp[lane + 64];
    float ss = x0 * x0 + x1 * x1;
#pragma unroll
    for (int off = 32; off; off >>= 1) ss += __shfl_xor(ss, off);
    const float sc = 1.f / fmaxf(sqrtf(ss), 1e-8f);
    ushort* op = out + (size_t)row * K_;
    op[lane] = f2b(x0 * sc);
    op[lane + 64] = f2b(x1 * sc);
}

// ---------------- banded cosine-sim + tags (fused; band-skip for compute) --------------

__global__ __launch_bounds__(256) void k_simtags(const ushort* __restrict__ normed,
                                                 const float* __restrict__ mask,
                                                 const int* __restrict__ Lp,
                                                 float* __restrict__ dis,
                                                 float* __restrict__ tags) {
    const int wid = threadIdx.x >> 6, lane = threadIdx.x & 63;
    const int l15 = lane & 15, lk = lane >> 4;
    const int b   = blockIdx.z;
    const int i0b = blockIdx.x * 64;
    const int i0  = i0b + wid * 16;
    const int j0  = blockIdx.y * 64;
    const int L   = *Lp;
    f32x4 acc[4] = {};
    if ((j0 + 63 >= i0b + 1) && (j0 <= i0b + 63 + L)) {
        const ushort* nb = normed + (size_t)b * S_ * K_;
#pragma unroll
        for (int kt = 0; kt < 4; ++kt) {
            const int kk = kt * 32;
            const short8 a = *(const short8*)(nb + (size_t)(i0 + l15) * K_ + kk + 8 * lk);
#pragma unroll
            for (int j = 0; j < 4; ++j) {
                const short8 bfr = *(const short8*)(nb + (size_t)(j0 + j * 16 + l15) * K_ + kk + 8 * lk);
                acc[j] = __builtin_amdgcn_mfma_f32_16x16x32_bf16(a, bfr, acc[j], 0, 0, 0);
            }
        }
    }
    const float* mb = mask + b * S_;
    float* dp = dis  + (size_t)b * S_ * S_;
    float* tp = tags + (size_t)b * S_ * S_;
#pragma unroll
    for (int j = 0; j < 4; ++j) {
#pragma unroll
        for (int jj = 0; jj < 4; ++jj) {
            const int i  = i0 + 4 * lk + jj;
            const int jc = j0 + j * 16 + l15;
            const int d  = jc - i;
            const bool band = (d >= 1 && d <= L);
            dp[(size_t)i * S_ + jc] = band ? acc[j][jj] : 0.f;
            tp[(size_t)i * S_ + jc] = band ? mb[i] * mb[jc] : 0.f;
        }
    }
}

// ---------------- host launch ----------------

extern "C" void kernel_launch(void* const* d_in, const int* in_sizes, int n_in,
                              void* d_out, int out_size, void* d_ws, size_t ws_size,
                              hipStream_t stream) {
    const float* rep  = (const float*)d_in[0];
    const float* mask = (const float*)d_in[1];
    const float* ew1  = (const float*)d_in[2];
    const float* ew3  = (const float*)d_in[3];
    const float* ew5  = (const float*)d_in[4];
    const float* lng  = (const float*)d_in[5];
    const float* lnb  = (const float*)d_in[6];
    const float* elin = (const float*)d_in[7];
    const float* etr  = (const float*)d_in[8];
    const float* dtr  = (const float*)d_in[9];
    const float* dw1  = (const float*)d_in[10];
    const float* dw3  = (const float*)d_in[11];
    const float* dw5  = (const float*)d_in[12];
    const float* dlin = (const float*)d_in[13];
    const float* olin = (const float*)d_in[14];

    float* out_loc = (float*)d_out;
    float* out_dis = out_loc + (size_t)B_ * S_ * K_;
    float* out_tag = out_dis + (size_t)B_ * S_ * S_;
    float* out_dec = out_tag + (size_t)B_ * S_ * S_;

    char* ws = (char*)d_ws;
    size_t off = 0;
    auto alloc = [&](size_t bytes) -> char* {
        char* p = ws + off;
        off += (bytes + 255) & ~(size_t)255;
        return p;
    };
    int*    Lp    = (int*)alloc(256);
    ushort* Xh    = (ushort*)alloc((size_t)B_ * SH_ * H_ * 2);  // enc input / dec d0 (halo'd)
    ushort* wte1  = (ushort*)alloc((size_t)C_ * 768 * 2);
    ushort* wte3  = (ushort*)alloc((size_t)C_ * 2304 * 2);
    ushort* wte5  = (ushort*)alloc((size_t)C_ * 3840 * 2);
    ushort* wtd1  = (ushort*)alloc((size_t)C_ * 768 * 2);
    ushort* wtd3  = (ushort*)alloc((size_t)C_ * 2304 * 2);
    ushort* wtd5  = (ushort*)alloc((size_t)C_ * 3840 * 2);
    ushort* welin = (ushort*)alloc((size_t)H_ * H_ * 2);
    ushort* wetr  = (ushort*)alloc((size_t)K_ * H_ * 2);
    ushort* wdtr  = (ushort*)alloc((size_t)H_ * K_ * 2);
    ushort* wdlin = (ushort*)alloc((size_t)H_ * H_ * 2);
    ushort* wolin = (ushort*)alloc((size_t)H_ * H_ * 2);
    ushort* bufB  = (ushort*)alloc((size_t)MTOK * H_ * 2);
    ushort* bufC  = (ushort*)alloc((size_t)MTOK * H_ * 2);
    ushort* bufD  = (ushort*)alloc((size_t)MTOK * H_ * 2);   // h2; aliased as PA (lifetimes disjoint)
    ushort* bufL  = (ushort*)alloc((size_t)MTOK * K_ * 2);
    ushort* bufN  = (ushort*)alloc((size_t)MTOK * K_ * 2);
    float*  PB    = (float*)alloc((size_t)MTOK * 256 * 4);
    float*  PA    = (float*)bufD;   // 16 MB inside bufD's 25 MB; bufD live only steps 5-6
    if (ws_size < off) return;

    // 1. max_act_len + halo'd bf16 input
    k_maxlen<<<1, 512, 0, stream>>>(mask, Lp);
    k_build_xh<<<2048, 256, 0, stream>>>(rep, Xh);

    // 2. all weight conversions, one launch
    CvtAll ca;
    ca.e[0]  = { ew1,  wte1, 768 * C_,  768 };
    ca.e[1]  = { ew3,  wte3, 2304 * C_, 2304 };
    ca.e[2]  = { ew5,  wte5, 3840 * C_, 3840 };
    ca.e[3]  = { dw1,  wtd1, 768 * C_,  768 };
    ca.e[4]  = { dw3,  wtd3, 2304 * C_, 2304 };
    ca.e[5]  = { dw5,  wtd5, 3840 * C_, 3840 };
    ca.e[6]  = { elin, welin, H_ * H_, 0 };
    ca.e[7]  = { etr,  wetr,  K_ * H_, 0 };
    ca.e[8]  = { dtr,  wdtr,  H_ * K_, 0 };
    ca.e[9]  = { dlin, wdlin, H_ * H_, 0 };
    ca.e[10] = { olin, wolin, H_ * H_, 0 };
    k_cvt_all<<<dim3(256, 11), 256, 0, stream>>>(ca);

    // 3. encoder convs: 256 equal-start blocks {k5a, k3, k5b, k1} -> bufB + PA/PB
    {
        GBP p{}; p.A = Xh; p.w1 = wte1; p.w3 = wte3; p.w5 = wte5;
        p.lda = H_; p.convB = bufB; p.PA = PA; p.PB = PB;
        gemm_big<true><<<256, 512, 0, stream>>>(p);
    }
    // 4. LN(conv + rep) -> bufC   (cols 512-767 from PA+PB)
    k_ln<<<MTOK, 192, 0, stream>>>(bufB, PA, PB, rep, lng, lnb, bufC);
    // 5. h2 = tanh(h_ln @ enc_lin^T) -> bufD
    {
        GBP p{}; p.A = bufC; p.W = welin; p.Ktot = H_; p.lda = H_;
        p.outB = bufD; p.ldoB = H_; p.act = 1;
        gemm_big<false><<<dim3(MTOK / 256, H_ / 256), 512, 0, stream>>>(p);
    }
    // 6. location = h2 @ enc_tr^T -> out_loc (f32) + bufL (bf16)
    {
        GemmP p{}; p.A = bufD; p.lda = H_; p.Wt = wetr; p.Ktot = H_;
        p.outF = out_loc; p.ldoF = K_; p.outB = bufL; p.ldoB = K_;
        gemm_lds<64, 128><<<dim3(MTOK / 64, 1), 256, 0, stream>>>(p);
    }
    // 7. normed -> bufN
    k_normed<<<MTOK / 4, 256, 0, stream>>>(out_loc, bufN);
    // 8. d0 = location @ dec_tr^T -> Xh interior (halo rows stay zero)
    {
        GemmP p{}; p.A = bufL; p.lda = K_; p.Wt = wdtr; p.Ktot = K_;
        p.outB = Xh; p.ldoB = H_; p.outB_halo = 1;
        gemm_lds<128, 128><<<dim3(MTOK / 128, H_ / 128), 256, 0, stream>>>(p);
    }
    // 9. decoder convs -> bufB + PA/PB   (bufD dead now; PA aliasing safe)
    {
        GBP p{}; p.A = Xh; p.w1 = wtd1; p.w3 = wtd3; p.w5 = wtd5;
        p.lda = H_; p.convB = bufB; p.PA = PA; p.PB = PB;
        gemm_big<true><<<256, 512, 0, stream>>>(p);
    }
    // 9.5 merge k5 partials into bufB cols 512-767
    k_merge<<<2048, 256, 0, stream>>>(PA, PB, bufB);
    // 10. d2 = tanh(d1 @ dec_lin^T) -> bufC
    {
        GBP p{}; p.A = bufB; p.W = wdlin; p.Ktot = H_; p.lda = H_;
        p.outB = bufC; p.ldoB = H_; p.act = 1;
        gemm_big<false><<<dim3(MTOK / 256, H_ / 256), 512, 0, stream>>>(p);
    }
    // 11. decode_out = d2 @ out_lin^T -> out_dec (f32)
    {
        GBP p{}; p.A = bufC; p.W = wolin; p.Ktot = H_; p.lda = H_;
        p.outF = out_dec; p.ldoF = H_;
        gemm_big<false><<<dim3(MTOK / 256, H_ / 256), 512, 0, stream>>>(p);
    }
    // 12. banded cosine sim + tags -> out_dis, out_tag
    k_simtags<<<dim3(S_ / 64, S_ / 64, B_), 256, 0, stream>>>(bufN, mask, Lp, out_dis, out_tag);
}

// Round 7
// 429.241 us; speedup vs baseline: 1.1340x; 1.1340x over previous
//
#include <hip/hip_runtime.h>

#define B_   8
#define S_   2048
#define H_   768
#define K_   128
#define C_   256
#define SH_  2052              // S + 4 halo rows (2 each side)
#define MTOK (B_*S_)           // 16384 tokens

typedef __attribute__((ext_vector_type(8))) short short8;
typedef __attribute__((ext_vector_type(4))) float f32x4;

typedef __attribute__((address_space(1))) const void gvoid;
typedef __attribute__((address_space(3))) void lvoid;

__device__ __forceinline__ void gload16(const void* g, void* l) {
    __builtin_amdgcn_global_load_lds((gvoid*)g, (lvoid*)l, 16, 0, 0);
}

__device__ __forceinline__ ushort f2b(float f) {
    union { float f; unsigned u; } v; v.f = f;
    unsigned r = v.u + 0x7fffu + ((v.u >> 16) & 1u);   // RNE
    return (ushort)(r >> 16);
}
__device__ __forceinline__ float b2f(ushort u) {
    union { unsigned u; float f; } v; v.u = ((unsigned)u) << 16;
    return v.f;
}
__device__ __forceinline__ float fast_tanh(float x) {
    float e = __expf(2.f * x);
    return 1.f - 2.f / (e + 1.f);
}

// ---------------- small prep kernels ----------------

__global__ __launch_bounds__(512) void k_maxlen(const float* __restrict__ mask, int* Lp) {
    __shared__ float sh[8];
    const int tid = threadIdx.x;
    float mx = 0.f;
    for (int b = 0; b < B_; ++b) {
        const float4 v = ((const float4*)(mask + b * S_))[tid];
        float s = v.x + v.y + v.z + v.w;
#pragma unroll
        for (int off = 32; off; off >>= 1) s += __shfl_xor(s, off);
        if ((tid & 63) == 0) sh[tid >> 6] = s;
        __syncthreads();
        if (tid == 0) {
            float t = 0.f;
#pragma unroll
            for (int q = 0; q < 8; ++q) t += sh[q];
            mx = fmaxf(mx, t);
        }
        __syncthreads();
    }
    if (tid == 0) *Lp = (int)mx;
}

// build halo'd bf16 copy of representation (vectorized x4)
__global__ void k_build_xh(const float* __restrict__ rep, ushort* __restrict__ xh) {
    int i = blockIdx.x * blockDim.x + threadIdx.x;
    const int stride = gridDim.x * blockDim.x;
    const int n4 = B_ * SH_ * H_ / 4;
    for (; i < n4; i += stride) {
        const int idx = i * 4;
        const int h = idx % H_;
        const int rs = idx / H_;
        const int s = rs % SH_;
        const int b = rs / SH_;
        ushort4 o; o.x = 0; o.y = 0; o.z = 0; o.w = 0;
        if (s >= 2 && s < S_ + 2) {
            const float4 v = *(const float4*)(rep + ((size_t)b * S_ + (s - 2)) * H_ + h);
            o.x = f2b(v.x); o.y = f2b(v.y); o.z = f2b(v.z); o.w = f2b(v.w);
        }
        *(ushort4*)(xh + idx) = o;
    }
}

// fused weight conversions: 11 entries in one launch
struct CvtE { const float* src; ushort* dst; int n; int kh; };  // kh=0: copy, else [KH][C]->[C][KH]
struct CvtAll { CvtE e[11]; };

__global__ void k_cvt_all(CvtAll a) {
    const CvtE e = a.e[blockIdx.y];
    int i = blockIdx.x * blockDim.x + threadIdx.x;
    const int stride = gridDim.x * blockDim.x;
    for (; i < e.n; i += stride) {
        if (e.kh) {
            const int c = i / e.kh;
            const int r = i - c * e.kh;
            e.dst[i] = f2b(e.src[r * C_ + c]);
        } else {
            e.dst[i] = f2b(e.src[i]);
        }
    }
}

// ---------------- g3: 8-wave, 3-deep-ring, counted-vmcnt MFMA GEMM (convs) ------------
// BM=128, BN=256, BK=64, 512 threads (8 waves as 2x4, each wave 64x64 output).

struct G3P {
    const ushort* A;
    const ushort* W0;   // conv: k=1 branch
    const ushort* W1;   // conv: k=3
    const ushort* W2;   // conv: k=5
    int lda;
    ushort* outB; int ldoB;
    int nMtiles;        // MTOK/128
};

__global__ __launch_bounds__(512, 2) void g3(G3P p) {
    constexpr int ASEG = 1024;               // 128 rows x 8 (16B segs)
    constexpr int BSEG = 2048;               // 256 rows x 8
    constexpr int BUFE = (ASEG + BSEG) * 8;  // ushorts per buffer (48 KB)
    __shared__ __align__(16) ushort lds[3][BUFE];

    const int tid = threadIdx.x;
    const int w = tid >> 6, lane = tid & 63;
    const int l15 = lane & 15, lk = lane >> 4;
    const int wr = w >> 2, wc = w & 3;       // 2 x 4 wave grid
    const int axor = l15 & 7;

    const int nM = p.nMtiles;
    int idx = blockIdx.x;
    int br;
    if (idx < nM) br = 2;                          // k=5 first (long pole)
    else if (idx < 2 * nM) { br = 1; idx -= nM; }
    else { br = 0; idx -= 2 * nM; }
    const int m_base = idx * 128;
    const int n_base = br * 256;
    const int nt = 12 * (2 * br + 1);
    const int Ktot = 768 * (2 * br + 1);
    const ushort* Wt = (br == 0) ? p.W0 : (br == 1) ? p.W1 : p.W2;
    const int arow0 = m_base + ((m_base >> 11) << 2) + (2 - br);   // halo'd row base

    auto stage1 = [&](int kt, int bufi, int q) {
        const int kk = kt << 6;
        const int tap = kt / 12;
        const int h0 = (kt - tap * 12) << 6;
        if (q < 2) {
            const int seg = q * 512 + tid;
            const int row = seg >> 3;
            const int slot = (seg & 7) ^ (row & 7);
            gload16(p.A + (size_t)(arow0 + tap + row) * p.lda + h0 + slot * 8,
                    &lds[bufi][seg * 8]);
        } else {
            const int seg = (q - 2) * 512 + tid;
            const int row = seg >> 3;
            const int slot = (seg & 7) ^ (row & 7);
            gload16(Wt + (size_t)row * Ktot + kk + slot * 8,
                    &lds[bufi][ASEG * 8 + seg * 8]);
        }
    };
    auto stage = [&](int kt, int bufi) {
#pragma unroll
        for (int q = 0; q < 6; ++q) stage1(kt, bufi, q);
    };

    f32x4 acc[4][4] = {};

    stage(0, 0);
    stage(1, 1);

    int buf = 0;
    for (int t = 0; t < nt; ++t) {
        const ushort* Ab = &lds[buf][0];
        const ushort* Bb = &lds[buf][ASEG * 8];
        if (t + 1 < nt) asm volatile("s_waitcnt vmcnt(6)" ::: "memory");
        else            asm volatile("s_waitcnt vmcnt(0)" ::: "memory");
        __builtin_amdgcn_sched_barrier(0);
        asm volatile("s_barrier" ::: "memory");   // tile t resident; tile t-1 reads done
        __builtin_amdgcn_sched_barrier(0);

        int nbuf = buf + 2; if (nbuf >= 3) nbuf -= 3;
        const bool sb = (t + 2 < nt);

#pragma unroll
        for (int ks = 0; ks < 2; ++ks) {
            short8 bq[4], aq[4];
#pragma unroll
            for (int ni = 0; ni < 4; ++ni)
                bq[ni] = *(const short8*)(Bb + (wc * 64 + ni * 16 + l15) * 64 + ((((ks << 2) | lk) ^ axor) << 3));
#pragma unroll
            for (int mi = 0; mi < 4; ++mi)
                aq[mi] = *(const short8*)(Ab + (wr * 64 + mi * 16 + l15) * 64 + ((((ks << 2) | lk) ^ axor) << 3));
            if (sb) { stage1(t + 2, nbuf, 3 * ks); stage1(t + 2, nbuf, 3 * ks + 1); stage1(t + 2, nbuf, 3 * ks + 2); }
            asm volatile("s_waitcnt lgkmcnt(0)" ::: "memory");
            __builtin_amdgcn_sched_barrier(0);
            __builtin_amdgcn_s_setprio(1);
#pragma unroll
            for (int mi = 0; mi < 4; ++mi)
#pragma unroll
                for (int ni = 0; ni < 4; ++ni)
                    acc[mi][ni] = __builtin_amdgcn_mfma_f32_16x16x32_bf16(aq[mi], bq[ni], acc[mi][ni], 0, 0, 0);
            __builtin_amdgcn_s_setprio(0);
            __builtin_amdgcn_sched_barrier(0);
        }
        ++buf; if (buf == 3) buf = 0;
    }

#pragma unroll
    for (int mi = 0; mi < 4; ++mi)
#pragma unroll
        for (int ni = 0; ni < 4; ++ni)
#pragma unroll
            for (int jj = 0; jj < 4; ++jj) {
                const int r = m_base + wr * 64 + mi * 16 + 4 * lk + jj;
                const int n = n_base + wc * 64 + ni * 16 + l15;
                p.outB[(size_t)r * p.ldoB + n] = f2b(acc[mi][ni][jj]);
            }
}

// ---------------- g4: 4-wave, BM=128 BN=192, 2-deep ring, 2 blocks/CU (linears) --------
// Wave grid 2x2, wave tile 64x96. Grid (128, 4) = 512 tiles = exact multiple of CU slots.

struct G4P {
    const ushort* A;
    const ushort* W;
    int Ktot;
    int lda;
    ushort* outB; int ldoB;
    float*  outF; int ldoF;
    int act;
};

__global__ __launch_bounds__(256, 2) void g4(G4P p) {
    constexpr int ASEG = 1024;   // 128 rows x 8
    constexpr int BSEG = 1536;   // 192 rows x 8
    __shared__ __align__(16) ushort lds[2][(ASEG + BSEG) * 8];   // 80 KB total

    const int tid = threadIdx.x;
    const int w = tid >> 6, lane = tid & 63;
    const int l15 = lane & 15, lk = lane >> 4;
    const int wr = w >> 1, wc = w & 1;
    const int axor = l15 & 7;
    const int m_base = blockIdx.x * 128;
    const int n_base = blockIdx.y * 192;
    const int nt = p.Ktot >> 6;

    auto stage = [&](int kt, int bufi) {
        const int kk = kt << 6;
        ushort* Ab = &lds[bufi][0];
        ushort* Bb = &lds[bufi][ASEG * 8];
#pragma unroll
        for (int q = 0; q < 4; ++q) {
            const int seg = q * 256 + tid;
            const int row = seg >> 3;
            const int s = (seg & 7) ^ (row & 7);
            gload16(p.A + (size_t)(m_base + row) * p.lda + kk + s * 8, Ab + seg * 8);
        }
#pragma unroll
        for (int q = 0; q < 6; ++q) {
            const int seg = q * 256 + tid;
            const int row = seg >> 3;
            const int s = (seg & 7) ^ (row & 7);
            gload16(p.W + (size_t)(n_base + row) * p.Ktot + kk + s * 8, Bb + seg * 8);
        }
    };

    f32x4 acc[4][6] = {};

    stage(0, 0);
    stage(1, 1);

    for (int t = 0; t < nt; ++t) {
        const int cur = t & 1;
        const ushort* Ab = &lds[cur][0];
        const ushort* Bb = &lds[cur][ASEG * 8];
        if (t + 1 < nt) asm volatile("s_waitcnt vmcnt(10)" ::: "memory");
        else            asm volatile("s_waitcnt vmcnt(0)" ::: "memory");
        __builtin_amdgcn_sched_barrier(0);
        asm volatile("s_barrier" ::: "memory");     // tile t resident for all waves
        __builtin_amdgcn_sched_barrier(0);

        short8 af[4][2], bf[6][2];
#pragma unroll
        for (int mi = 0; mi < 4; ++mi)
#pragma unroll
            for (int ks = 0; ks < 2; ++ks)
                af[mi][ks] = *(const short8*)(Ab + (wr * 64 + mi * 16 + l15) * 64 + ((((ks << 2) | lk) ^ axor) << 3));
#pragma unroll
        for (int ni = 0; ni < 6; ++ni)
#pragma unroll
            for (int ks = 0; ks < 2; ++ks)
                bf[ni][ks] = *(const short8*)(Bb + (wc * 96 + ni * 16 + l15) * 64 + ((((ks << 2) | lk) ^ axor) << 3));
        asm volatile("s_waitcnt lgkmcnt(0)" ::: "memory");
        __builtin_amdgcn_sched_barrier(0);
        asm volatile("s_barrier" ::: "memory");     // all waves done reading buf[cur]
        __builtin_amdgcn_sched_barrier(0);
        if (t + 2 < nt) stage(t + 2, cur);          // overwrite drained buffer under MFMA
        __builtin_amdgcn_sched_barrier(0);
        __builtin_amdgcn_s_setprio(1);
#pragma unroll
        for (int mi = 0; mi < 4; ++mi)
#pragma unroll
            for (int ni = 0; ni < 6; ++ni) {
                acc[mi][ni] = __builtin_amdgcn_mfma_f32_16x16x32_bf16(af[mi][0], bf[ni][0], acc[mi][ni], 0, 0, 0);
                acc[mi][ni] = __builtin_amdgcn_mfma_f32_16x16x32_bf16(af[mi][1], bf[ni][1], acc[mi][ni], 0, 0, 0);
            }
        __builtin_amdgcn_s_setprio(0);
        __builtin_amdgcn_sched_barrier(0);
    }

#pragma unroll
    for (int mi = 0; mi < 4; ++mi)
#pragma unroll
        for (int ni = 0; ni < 6; ++ni)
#pragma unroll
            for (int jj = 0; jj < 4; ++jj) {
                const int r = m_base + wr * 64 + mi * 16 + 4 * lk + jj;
                const int n = n_base + wc * 96 + ni * 16 + l15;
                float v = acc[mi][ni][jj];
                if (p.act) v = fast_tanh(v);
                if (p.outF) p.outF[(size_t)r * p.ldoF + n] = v;
                if (p.outB) p.outB[(size_t)r * p.ldoB + n] = f2b(v);
            }
}

// ---------------- small LDS-staged GEMM (m97 2-phase) for N=128 / K=128 cases ----------

struct GemmP {
    const ushort* A;
    const ushort* Wt;
    int Ktot;
    int lda;
    ushort* outB;
    int ldoB;
    int outB_halo;      // row' = r + 4*(r>>11) + 2
    float* outF;
    int ldoF;
    int act;
};

template<int BM, int BN>
__global__ __launch_bounds__(256) void gemm_lds(GemmP p) {
    constexpr int MF = BM / 32;
    constexpr int NF = BN / 32;
    __shared__ __align__(16) ushort As[BM * 64];
    __shared__ __align__(16) ushort Bs[BN * 64];
    const int tid = threadIdx.x;
    const int w = tid >> 6, lane = tid & 63;
    const int l15 = lane & 15, lk = lane >> 4;
    const int m_base = blockIdx.x * BM;
    const int n_base = blockIdx.y * BN;
    const int wr = w >> 1, wc = w & 1;
    f32x4 acc[MF][NF] = {};
    const int srow = lane >> 3;
    const int scol = (lane & 7) * 8;
    const int nk = p.Ktot >> 6;

    for (int kt = 0; kt < nk; ++kt) {
        const int kk = kt << 6;
#pragma unroll
        for (int q = 0; q < BM / 32; ++q) {
            const int r = w * (BM / 4) + q * 8;
            gload16(p.A + (size_t)(m_base + r + srow) * p.lda + kk + scol, As + r * 64);
        }
#pragma unroll
        for (int q = 0; q < BN / 32; ++q) {
            const int r = w * (BN / 4) + q * 8;
            gload16(p.Wt + (size_t)(n_base + r + srow) * p.Ktot + kk + scol, Bs + r * 64);
        }
        __syncthreads();
#pragma unroll
        for (int ks = 0; ks < 2; ++ks) {
            short8 af[MF], bfr[NF];
#pragma unroll
            for (int i = 0; i < MF; ++i)
                af[i] = *(const short8*)(As + (wr * (BM / 2) + i * 16 + l15) * 64 + ks * 32 + 8 * lk);
#pragma unroll
            for (int j = 0; j < NF; ++j)
                bfr[j] = *(const short8*)(Bs + (wc * (BN / 2) + j * 16 + l15) * 64 + ks * 32 + 8 * lk);
#pragma unroll
            for (int i = 0; i < MF; ++i)
#pragma unroll
                for (int j = 0; j < NF; ++j)
                    acc[i][j] = __builtin_amdgcn_mfma_f32_16x16x32_bf16(af[i], bfr[j], acc[i][j], 0, 0, 0);
        }
        __syncthreads();
    }

    const int bb4 = ((m_base >> 11) << 2) + 2;
#pragma unroll
    for (int i = 0; i < MF; ++i)
#pragma unroll
        for (int j = 0; j < NF; ++j)
#pragma unroll
            for (int jj = 0; jj < 4; ++jj) {
                const int r = m_base + wr * (BM / 2) + i * 16 + 4 * lk + jj;
                const int n = n_base + wc * (BN / 2) + j * 16 + l15;
                float v = acc[i][j][jj];
                if (p.act) v = fast_tanh(v);
                if (p.outF) p.outF[(size_t)r * p.ldoF + n] = v;
                if (p.outB) {
                    const int rr = p.outB_halo ? (r + bb4) : r;
                    p.outB[(size_t)rr * p.ldoB + n] = f2b(v);
                }
            }
}

// ---------------- LayerNorm(conv_out + residual) -> bf16 (vectorized, 192 thr/row) -----

__global__ __launch_bounds__(192) void k_ln(const ushort* __restrict__ conv,
                                            const float* __restrict__ rep,
                                            const float* __restrict__ gw,
                                            const float* __restrict__ bw,
                                            ushort* __restrict__ out) {
    const int row = blockIdx.x;
    const int tid = threadIdx.x;
    const int h = tid * 4;
    const ushort4 cv = *(const ushort4*)(conv + (size_t)row * H_ + h);
    const float4  rv = *(const float4*)(rep + (size_t)row * H_ + h);
    float v[4] = { b2f(cv.x) + rv.x, b2f(cv.y) + rv.y, b2f(cv.z) + rv.z, b2f(cv.w) + rv.w };
    float s1 = v[0] + v[1] + v[2] + v[3];
    float s2 = v[0]*v[0] + v[1]*v[1] + v[2]*v[2] + v[3]*v[3];
#pragma unroll
    for (int off = 32; off; off >>= 1) { s1 += __shfl_xor(s1, off); s2 += __shfl_xor(s2, off); }
    __shared__ float sh[6];
    const int wid = tid >> 6, lane = tid & 63;
    if (lane == 0) { sh[wid] = s1; sh[3 + wid] = s2; }
    __syncthreads();
    s1 = sh[0] + sh[1] + sh[2];
    s2 = sh[3] + sh[4] + sh[5];
    const float mu  = s1 * (1.f / H_);
    const float var = s2 * (1.f / H_) - mu * mu;
    const float rs  = rsqrtf(var + 1e-5f);
    const float4 gv = *(const float4*)(gw + h);
    const float4 bv = *(const float4*)(bw + h);
    ushort4 o;
    o.x = f2b((v[0] - mu) * rs * gv.x + bv.x);
    o.y = f2b((v[1] - mu) * rs * gv.y + bv.y);
    o.z = f2b((v[2] - mu) * rs * gv.z + bv.z);
    o.w = f2b((v[3] - mu) * rs * gv.w + bv.w);
    *(ushort4*)(out + (size_t)row * H_ + h) = o;
}

// ---------------- row-normalize location -> bf16 ----------------

__global__ __launch_bounds__(256) void k_normed(const float* __restrict__ loc, ushort* __restrict__ out) {
    const int wid = threadIdx.x >> 6, lane = threadIdx.x & 63;
    const int row = blockIdx.x * 4 + wid;
    const float* lp = loc + (size_t)row * K_;
    const float x0 = lp[lane], x1 = lp[lane + 64];
    float ss = x0 * x0 + x1 * x1;
#pragma unroll
    for (int off = 32; off; off >>= 1) ss += __shfl_xor(ss, off);
    const float sc = 1.f / fmaxf(sqrtf(ss), 1e-8f);
    ushort* op = out + (size_t)row * K_;
    op[lane] = f2b(x0 * sc);
    op[lane + 64] = f2b(x1 * sc);
}

// ---------------- banded cosine-sim + tags (fused; band-skip for compute) --------------

__global__ __launch_bounds__(256) void k_simtags(const ushort* __restrict__ normed,
                                                 const float* __restrict__ mask,
                                                 const int* __restrict__ Lp,
                                                 float* __restrict__ dis,
                                                 float* __restrict__ tags) {
    const int wid = threadIdx.x >> 6, lane = threadIdx.x & 63;
    const int l15 = lane & 15, lk = lane >> 4;
    const int b   = blockIdx.z;
    const int i0b = blockIdx.x * 64;
    const int i0  = i0b + wid * 16;
    const int j0  = blockIdx.y * 64;
    const int L   = *Lp;
    f32x4 acc[4] = {};
    if ((j0 + 63 >= i0b + 1) && (j0 <= i0b + 63 + L)) {
        const ushort* nb = normed + (size_t)b * S_ * K_;
#pragma unroll
        for (int kt = 0; kt < 4; ++kt) {
            const int kk = kt * 32;
            const short8 a = *(const short8*)(nb + (size_t)(i0 + l15) * K_ + kk + 8 * lk);
#pragma unroll
            for (int j = 0; j < 4; ++j) {
                const short8 bfr = *(const short8*)(nb + (size_t)(j0 + j * 16 + l15) * K_ + kk + 8 * lk);
                acc[j] = __builtin_amdgcn_mfma_f32_16x16x32_bf16(a, bfr, acc[j], 0, 0, 0);
            }
        }
    }
    const float* mb = mask + b * S_;
    float* dp = dis  + (size_t)b * S_ * S_;
    float* tp = tags + (size_t)b * S_ * S_;
#pragma unroll
    for (int j = 0; j < 4; ++j) {
#pragma unroll
        for (int jj = 0; jj < 4; ++jj) {
            const int i  = i0 + 4 * lk + jj;
            const int jc = j0 + j * 16 + l15;
            const int d  = jc - i;
            const bool band = (d >= 1 && d <= L);
            dp[(size_t)i * S_ + jc] = band ? acc[j][jj] : 0.f;
            tp[(size_t)i * S_ + jc] = band ? mb[i] * mb[jc] : 0.f;
        }
    }
}

// ---------------- host launch ----------------

extern "C" void kernel_launch(void* const* d_in, const int* in_sizes, int n_in,
                              void* d_out, int out_size, void* d_ws, size_t ws_size,
                              hipStream_t stream) {
    const float* rep  = (const float*)d_in[0];
    const float* mask = (const float*)d_in[1];
    const float* ew1  = (const float*)d_in[2];
    const float* ew3  = (const float*)d_in[3];
    const float* ew5  = (const float*)d_in[4];
    const float* lng  = (const float*)d_in[5];
    const float* lnb  = (const float*)d_in[6];
    const float* elin = (const float*)d_in[7];
    const float* etr  = (const float*)d_in[8];
    const float* dtr  = (const float*)d_in[9];
    const float* dw1  = (const float*)d_in[10];
    const float* dw3  = (const float*)d_in[11];
    const float* dw5  = (const float*)d_in[12];
    const float* dlin = (const float*)d_in[13];
    const float* olin = (const float*)d_in[14];

    float* out_loc = (float*)d_out;
    float* out_dis = out_loc + (size_t)B_ * S_ * K_;
    float* out_tag = out_dis + (size_t)B_ * S_ * S_;
    float* out_dec = out_tag + (size_t)B_ * S_ * S_;

    char* ws = (char*)d_ws;
    size_t off = 0;
    auto alloc = [&](size_t bytes) -> char* {
        char* p = ws + off;
        off += (bytes + 255) & ~(size_t)255;
        return p;
    };
    int*    Lp    = (int*)alloc(256);
    ushort* Xh    = (ushort*)alloc((size_t)B_ * SH_ * H_ * 2);  // enc input / dec d0 (halo'd)
    ushort* wte1  = (ushort*)alloc((size_t)C_ * 768 * 2);
    ushort* wte3  = (ushort*)alloc((size_t)C_ * 2304 * 2);
    ushort* wte5  = (ushort*)alloc((size_t)C_ * 3840 * 2);
    ushort* wtd1  = (ushort*)alloc((size_t)C_ * 768 * 2);
    ushort* wtd3  = (ushort*)alloc((size_t)C_ * 2304 * 2);
    ushort* wtd5  = (ushort*)alloc((size_t)C_ * 3840 * 2);
    ushort* welin = (ushort*)alloc((size_t)H_ * H_ * 2);
    ushort* wetr  = (ushort*)alloc((size_t)K_ * H_ * 2);
    ushort* wdtr  = (ushort*)alloc((size_t)H_ * K_ * 2);
    ushort* wdlin = (ushort*)alloc((size_t)H_ * H_ * 2);
    ushort* wolin = (ushort*)alloc((size_t)H_ * H_ * 2);
    ushort* bufB  = (ushort*)alloc((size_t)MTOK * H_ * 2);
    ushort* bufC  = (ushort*)alloc((size_t)MTOK * H_ * 2);
    ushort* bufD  = (ushort*)alloc((size_t)MTOK * H_ * 2);
    ushort* bufL  = (ushort*)alloc((size_t)MTOK * K_ * 2);
    ushort* bufN  = (ushort*)alloc((size_t)MTOK * K_ * 2);
    if (ws_size < off) return;

    // 1. max_act_len + halo'd bf16 input
    k_maxlen<<<1, 512, 0, stream>>>(mask, Lp);
    k_build_xh<<<2048, 256, 0, stream>>>(rep, Xh);

    // 2. all weight conversions, one launch
    CvtAll ca;
    ca.e[0]  = { ew1,  wte1, 768 * C_,  768 };
    ca.e[1]  = { ew3,  wte3, 2304 * C_, 2304 };
    ca.e[2]  = { ew5,  wte5, 3840 * C_, 3840 };
    ca.e[3]  = { dw1,  wtd1, 768 * C_,  768 };
    ca.e[4]  = { dw3,  wtd3, 2304 * C_, 2304 };
    ca.e[5]  = { dw5,  wtd5, 3840 * C_, 3840 };
    ca.e[6]  = { elin, welin, H_ * H_, 0 };
    ca.e[7]  = { etr,  wetr,  K_ * H_, 0 };
    ca.e[8]  = { dtr,  wdtr,  H_ * K_, 0 };
    ca.e[9]  = { dlin, wdlin, H_ * H_, 0 };
    ca.e[10] = { olin, wolin, H_ * H_, 0 };
    k_cvt_all<<<dim3(256, 11), 256, 0, stream>>>(ca);

    // 3. encoder convs (fused 3 branches, k=5 first) -> bufB
    {
        G3P p{}; p.A = Xh; p.W0 = wte1; p.W1 = wte3; p.W2 = wte5;
        p.lda = H_; p.outB = bufB; p.ldoB = H_; p.nMtiles = MTOK / 128;
        g3<<<3 * (MTOK / 128), 512, 0, stream>>>(p);
    }
    // 4. LN(conv + rep) -> bufC
    k_ln<<<MTOK, 192, 0, stream>>>(bufB, rep, lng, lnb, bufC);
    // 5. h2 = tanh(h_ln @ enc_lin^T) -> bufD
    {
        G4P p{}; p.A = bufC; p.W = welin; p.Ktot = H_; p.lda = H_;
        p.outB = bufD; p.ldoB = H_; p.act = 1;
        g4<<<dim3(MTOK / 128, H_ / 192), 256, 0, stream>>>(p);
    }
    // 6. location = h2 @ enc_tr^T -> out_loc (f32) + bufL (bf16)
    {
        GemmP p{}; p.A = bufD; p.lda = H_; p.Wt = wetr; p.Ktot = H_;
        p.outF = out_loc; p.ldoF = K_; p.outB = bufL; p.ldoB = K_;
        gemm_lds<64, 128><<<dim3(MTOK / 64, 1), 256, 0, stream>>>(p);
    }
    // 7. normed -> bufN
    k_normed<<<MTOK / 4, 256, 0, stream>>>(out_loc, bufN);
    // 8. d0 = location @ dec_tr^T -> Xh interior (halo rows stay zero)
    {
        GemmP p{}; p.A = bufL; p.lda = K_; p.Wt = wdtr; p.Ktot = K_;
        p.outB = Xh; p.ldoB = H_; p.outB_halo = 1;
        gemm_lds<128, 128><<<dim3(MTOK / 128, H_ / 128), 256, 0, stream>>>(p);
    }
    // 9. decoder convs -> bufB
    {
        G3P p{}; p.A = Xh; p.W0 = wtd1; p.W1 = wtd3; p.W2 = wtd5;
        p.lda = H_; p.outB = bufB; p.ldoB = H_; p.nMtiles = MTOK / 128;
        g3<<<3 * (MTOK / 128), 512, 0, stream>>>(p);
    }
    // 10. d2 = tanh(d1 @ dec_lin^T) -> bufC
    {
        G4P p{}; p.A = bufB; p.W = wdlin; p.Ktot = H_; p.lda = H_;
        p.outB = bufC; p.ldoB = H_; p.act = 1;
        g4<<<dim3(MTOK / 128, H_ / 192), 256, 0, stream>>>(p);
    }
    // 11. decode_out = d2 @ out_lin^T -> out_dec (f32)
    {
        G4P p{}; p.A = bufC; p.W = wolin; p.Ktot = H_; p.lda = H_;
        p.outF = out_dec; p.ldoF = H_;
        g4<<<dim3(MTOK / 128, H_ / 192), 256, 0, stream>>>(p);
    }
    // 12. banded cosine sim + tags -> out_dis, out_tag
    k_simtags<<<dim3(S_ / 64, S_ / 64, B_), 256, 0, stream>>>(bufN, mask, Lp, out_dis, out_tag);
}

// Round 8
// 386.930 us; speedup vs baseline: 1.2580x; 1.1094x over previous
//
#include <hip/hip_runtime.h>

#define B_   8
#define S_   2048
#define H_   768
#define K_   128
#define C_   256
#define SH_  2052              // S + 4 halo rows (2 each side)
#define MTOK (B_*S_)           // 16384 tokens

typedef __attribute__((ext_vector_type(8))) short short8;
typedef __attribute__((ext_vector_type(4))) float f32x4;

typedef __attribute__((address_space(1))) const void gvoid;
typedef __attribute__((address_space(3))) void lvoid;

__device__ __forceinline__ void gload16(const void* g, void* l) {
    __builtin_amdgcn_global_load_lds((gvoid*)g, (lvoid*)l, 16, 0, 0);
}

__device__ __forceinline__ ushort f2b(float f) {
    union { float f; unsigned u; } v; v.f = f;
    unsigned r = v.u + 0x7fffu + ((v.u >> 16) & 1u);   // RNE
    return (ushort)(r >> 16);
}
__device__ __forceinline__ float b2f(ushort u) {
    union { unsigned u; float f; } v; v.u = ((unsigned)u) << 16;
    return v.f;
}
__device__ __forceinline__ float fast_tanh(float x) {
    float e = __expf(2.f * x);
    return 1.f - 2.f / (e + 1.f);
}

// ---------------- small prep kernels ----------------

// max_act_len + zero the halo rows of the halo'd location buffer
__global__ __launch_bounds__(512) void k_maxlen(const float* __restrict__ mask, int* Lp,
                                                ushort* __restrict__ lh) {
    __shared__ float sh[8];
    const int tid = threadIdx.x;
    float mx = 0.f;
    for (int b = 0; b < B_; ++b) {
        const float4 v = ((const float4*)(mask + b * S_))[tid];
        float s = v.x + v.y + v.z + v.w;
#pragma unroll
        for (int off = 32; off; off >>= 1) s += __shfl_xor(s, off);
        if ((tid & 63) == 0) sh[tid >> 6] = s;
        __syncthreads();
        if (tid == 0) {
            float t = 0.f;
#pragma unroll
            for (int q = 0; q < 8; ++q) t += sh[q];
            mx = fmaxf(mx, t);
        }
        __syncthreads();
    }
    if (tid == 0) *Lp = (int)mx;
    // zero halo rows {0,1,2050,2051} x 128 cols per batch
    for (int i = tid; i < B_ * 4 * K_; i += 512) {
        const int b = i >> 9;
        const int rc = i & 511;
        const int rr = rc >> 7;
        const int cc = rc & 127;
        const int row = (rr < 2) ? rr : (2048 + rr);
        lh[((size_t)b * SH_ + row) * K_ + cc] = 0;
    }
}

// build halo'd bf16 copy of representation (vectorized x4)
__global__ void k_build_xh(const float* __restrict__ rep, ushort* __restrict__ xh) {
    int i = blockIdx.x * blockDim.x + threadIdx.x;
    const int stride = gridDim.x * blockDim.x;
    const int n4 = B_ * SH_ * H_ / 4;
    for (; i < n4; i += stride) {
        const int idx = i * 4;
        const int h = idx % H_;
        const int rs = idx / H_;
        const int s = rs % SH_;
        const int b = rs / SH_;
        ushort4 o; o.x = 0; o.y = 0; o.z = 0; o.w = 0;
        if (s >= 2 && s < S_ + 2) {
            const float4 v = *(const float4*)(rep + ((size_t)b * S_ + (s - 2)) * H_ + h);
            o.x = f2b(v.x); o.y = f2b(v.y); o.z = f2b(v.z); o.w = f2b(v.w);
        }
        *(ushort4*)(xh + idx) = o;
    }
}

// fused weight conversions: kh=0 copy; else dst[c][r] = src[r*sld + c]  (transpose)
struct CvtE { const float* src; ushort* dst; int n; int kh; int sld; };
struct CvtAll { CvtE e[11]; };

__global__ void k_cvt_all(CvtAll a) {
    const CvtE e = a.e[blockIdx.y];
    int i = blockIdx.x * blockDim.x + threadIdx.x;
    const int stride = gridDim.x * blockDim.x;
    for (; i < e.n; i += stride) {
        if (e.kh) {
            const int c = i / e.kh;
            const int r = i - c * e.kh;
            e.dst[i] = f2b(e.src[r * e.sld + c]);
        } else {
            e.dst[i] = f2b(e.src[i]);
        }
    }
}

// ---------------- k_compw: composite decoder weights w'[t] = dec_tr^T @ w[t] ----------
// grid (2 n-tiles, 9 taps), 256 thr. Output written TRANSPOSED: o[c][koff + j].

struct CompE { const ushort* w; int wld; int woff; ushort* o; int old_; int koff; };
struct CompP { const ushort* dtrT; CompE e[9]; };

__global__ __launch_bounds__(256) void k_compw(CompP p) {
    __shared__ __align__(16) ushort As[128 * 64];
    __shared__ __align__(16) ushort Bs[128 * 64];
    const CompE e = p.e[blockIdx.y];
    const int tid = threadIdx.x;
    const int w = tid >> 6, lane = tid & 63;
    const int l15 = lane & 15, lk = lane >> 4;
    const int wr = w >> 1, wc = w & 1;
    const int n_base = blockIdx.x * 128;
    f32x4 acc[4][4] = {};
    const int srow = lane >> 3;
    const int scol = (lane & 7) * 8;

    for (int kt = 0; kt < 12; ++kt) {
        const int kk = kt << 6;
#pragma unroll
        for (int q = 0; q < 4; ++q) {
            const int r = w * 32 + q * 8;
            gload16(p.dtrT + (size_t)(r + srow) * 768 + kk + scol, As + r * 64);
            gload16(e.w + (size_t)(n_base + r + srow) * e.wld + e.woff + kk + scol, Bs + r * 64);
        }
        __syncthreads();
#pragma unroll
        for (int ks = 0; ks < 2; ++ks) {
            short8 af[4], bfr[4];
#pragma unroll
            for (int i = 0; i < 4; ++i)
                af[i] = *(const short8*)(As + (wr * 64 + i * 16 + l15) * 64 + ks * 32 + 8 * lk);
#pragma unroll
            for (int j = 0; j < 4; ++j)
                bfr[j] = *(const short8*)(Bs + (wc * 64 + j * 16 + l15) * 64 + ks * 32 + 8 * lk);
#pragma unroll
            for (int i = 0; i < 4; ++i)
#pragma unroll
                for (int j = 0; j < 4; ++j)
                    acc[i][j] = __builtin_amdgcn_mfma_f32_16x16x32_bf16(af[i], bfr[j], acc[i][j], 0, 0, 0);
        }
        __syncthreads();
    }
#pragma unroll
    for (int i = 0; i < 4; ++i)
#pragma unroll
        for (int j = 0; j < 4; ++j)
#pragma unroll
            for (int jj = 0; jj < 4; ++jj) {
                const int jr = wr * 64 + i * 16 + 4 * lk + jj;       // j index 0..127
                const int c  = n_base + wc * 64 + j * 16 + l15;      // channel 0..255
                e.o[(size_t)c * e.old_ + e.koff + jr] = f2b(acc[i][j][jj]);
            }
}

// ---------------- g3: 8-wave, 3-deep-ring, counted-vmcnt conv GEMM --------------------
// BM=128, BN=256, BK=64, 512 threads (2x4 waves, wave 64x64).
// DEC=false: A = halo'd rep [.][768], K/tap = 768 (12 tiles). DEC=true: A = halo'd
// location [.][128], composite weights, K/tap = 128 (2 tiles).

struct G3P {
    const ushort* A;
    const ushort* W0;   // k=1 weights [256][1*KD]
    const ushort* W1;   // k=3 [256][3*KD]
    const ushort* W2;   // k=5 [256][5*KD]
    int lda;
    ushort* outB; int ldoB;
    int nMtiles;        // MTOK/128
};

template<bool DEC>
__global__ __launch_bounds__(512, 2) void g3(G3P p) {
    constexpr int TPT = DEC ? 2 : 12;        // K-tiles per tap
    constexpr int LDA = DEC ? 128 : 768;
    constexpr int ASEG = 1024;               // 128 rows x 8 (16B segs)
    constexpr int BSEG = 2048;               // 256 rows x 8
    constexpr int BUFE = (ASEG + BSEG) * 8;
    __shared__ __align__(16) ushort lds[3][BUFE];

    const int tid = threadIdx.x;
    const int w = tid >> 6, lane = tid & 63;
    const int l15 = lane & 15, lk = lane >> 4;
    const int wr = w >> 2, wc = w & 3;
    const int axor = l15 & 7;

    const int nM = p.nMtiles;
    int idx = blockIdx.x;
    int br;
    if (idx < nM) br = 2;                          // k=5 first (long pole)
    else if (idx < 2 * nM) { br = 1; idx -= nM; }
    else { br = 0; idx -= 2 * nM; }
    const int m_base = idx * 128;
    const int n_base = br * 256;
    const int nt = TPT * (2 * br + 1);
    const int Ktot = LDA * (2 * br + 1);           // weight row stride
    const ushort* Wt = (br == 0) ? p.W0 : (br == 1) ? p.W1 : p.W2;
    const int arow0 = m_base + ((m_base >> 11) << 2) + (2 - br);   // halo'd row base

    auto stage1 = [&](int kt, int bufi, int q) {
        const int tap = kt / TPT;
        const int h0 = (kt - tap * TPT) << 6;
        if (q < 2) {
            const int seg = q * 512 + tid;
            const int row = seg >> 3;
            const int slot = (seg & 7) ^ (row & 7);
            gload16(p.A + (size_t)(arow0 + tap + row) * LDA + h0 + slot * 8,
                    &lds[bufi][seg * 8]);
        } else {
            const int seg = (q - 2) * 512 + tid;
            const int row = seg >> 3;
            const int slot = (seg & 7) ^ (row & 7);
            gload16(Wt + (size_t)row * Ktot + (kt << 6) + slot * 8,
                    &lds[bufi][ASEG * 8 + seg * 8]);
        }
    };
    auto stage = [&](int kt, int bufi) {
#pragma unroll
        for (int q = 0; q < 6; ++q) stage1(kt, bufi, q);
    };

    f32x4 acc[4][4] = {};

    stage(0, 0);
    stage(1, 1);

    int buf = 0;
    for (int t = 0; t < nt; ++t) {
        const ushort* Ab = &lds[buf][0];
        const ushort* Bb = &lds[buf][ASEG * 8];
        if (t + 1 < nt) asm volatile("s_waitcnt vmcnt(6)" ::: "memory");
        else            asm volatile("s_waitcnt vmcnt(0)" ::: "memory");
        __builtin_amdgcn_sched_barrier(0);
        asm volatile("s_barrier" ::: "memory");   // tile t resident; tile t-1 reads done
        __builtin_amdgcn_sched_barrier(0);

        int nbuf = buf + 2; if (nbuf >= 3) nbuf -= 3;
        const bool sb = (t + 2 < nt);

#pragma unroll
        for (int ks = 0; ks < 2; ++ks) {
            short8 bq[4], aq[4];
#pragma unroll
            for (int ni = 0; ni < 4; ++ni)
                bq[ni] = *(const short8*)(Bb + (wc * 64 + ni * 16 + l15) * 64 + ((((ks << 2) | lk) ^ axor) << 3));
#pragma unroll
            for (int mi = 0; mi < 4; ++mi)
                aq[mi] = *(const short8*)(Ab + (wr * 64 + mi * 16 + l15) * 64 + ((((ks << 2) | lk) ^ axor) << 3));
            if (sb) { stage1(t + 2, nbuf, 3 * ks); stage1(t + 2, nbuf, 3 * ks + 1); stage1(t + 2, nbuf, 3 * ks + 2); }
            asm volatile("s_waitcnt lgkmcnt(0)" ::: "memory");
            __builtin_amdgcn_sched_barrier(0);
            __builtin_amdgcn_s_setprio(1);
#pragma unroll
            for (int mi = 0; mi < 4; ++mi)
#pragma unroll
                for (int ni = 0; ni < 4; ++ni)
                    acc[mi][ni] = __builtin_amdgcn_mfma_f32_16x16x32_bf16(aq[mi], bq[ni], acc[mi][ni], 0, 0, 0);
            __builtin_amdgcn_s_setprio(0);
            __builtin_amdgcn_sched_barrier(0);
        }
        ++buf; if (buf == 3) buf = 0;
    }

#pragma unroll
    for (int mi = 0; mi < 4; ++mi)
#pragma unroll
        for (int ni = 0; ni < 4; ++ni)
#pragma unroll
            for (int jj = 0; jj < 4; ++jj) {
                const int r = m_base + wr * 64 + mi * 16 + 4 * lk + jj;
                const int n = n_base + wc * 64 + ni * 16 + l15;
                p.outB[(size_t)r * p.ldoB + n] = f2b(acc[mi][ni][jj]);
            }
}

// ---------------- g4: 4-wave, BM=128 BN=192, 2-deep ring, 2 blocks/CU (linears) --------

struct G4P {
    const ushort* A;
    const ushort* W;
    int Ktot;
    int lda;
    ushort* outB; int ldoB;
    float*  outF; int ldoF;
    int act;
};

__global__ __launch_bounds__(256, 2) void g4(G4P p) {
    constexpr int ASEG = 1024;   // 128 rows x 8
    constexpr int BSEG = 1536;   // 192 rows x 8
    __shared__ __align__(16) ushort lds[2][(ASEG + BSEG) * 8];   // 80 KB total

    const int tid = threadIdx.x;
    const int w = tid >> 6, lane = tid & 63;
    const int l15 = lane & 15, lk = lane >> 4;
    const int wr = w >> 1, wc = w & 1;
    const int axor = l15 & 7;
    const int m_base = blockIdx.x * 128;
    const int n_base = blockIdx.y * 192;
    const int nt = p.Ktot >> 6;

    auto stage = [&](int kt, int bufi) {
        const int kk = kt << 6;
        ushort* Ab = &lds[bufi][0];
        ushort* Bb = &lds[bufi][ASEG * 8];
#pragma unroll
        for (int q = 0; q < 4; ++q) {
            const int seg = q * 256 + tid;
            const int row = seg >> 3;
            const int s = (seg & 7) ^ (row & 7);
            gload16(p.A + (size_t)(m_base + row) * p.lda + kk + s * 8, Ab + seg * 8);
        }
#pragma unroll
        for (int q = 0; q < 6; ++q) {
            const int seg = q * 256 + tid;
            const int row = seg >> 3;
            const int s = (seg & 7) ^ (row & 7);
            gload16(p.W + (size_t)(n_base + row) * p.Ktot + kk + s * 8, Bb + seg * 8);
        }
    };

    f32x4 acc[4][6] = {};

    stage(0, 0);
    stage(1, 1);

    for (int t = 0; t < nt; ++t) {
        const int cur = t & 1;
        const ushort* Ab = &lds[cur][0];
        const ushort* Bb = &lds[cur][ASEG * 8];
        if (t + 1 < nt) asm volatile("s_waitcnt vmcnt(10)" ::: "memory");
        else            asm volatile("s_waitcnt vmcnt(0)" ::: "memory");
        __builtin_amdgcn_sched_barrier(0);
        asm volatile("s_barrier" ::: "memory");     // tile t resident for all waves
        __builtin_amdgcn_sched_barrier(0);

        short8 af[4][2], bf[6][2];
#pragma unroll
        for (int mi = 0; mi < 4; ++mi)
#pragma unroll
            for (int ks = 0; ks < 2; ++ks)
                af[mi][ks] = *(const short8*)(Ab + (wr * 64 + mi * 16 + l15) * 64 + ((((ks << 2) | lk) ^ axor) << 3));
#pragma unroll
        for (int ni = 0; ni < 6; ++ni)
#pragma unroll
            for (int ks = 0; ks < 2; ++ks)
                bf[ni][ks] = *(const short8*)(Bb + (wc * 96 + ni * 16 + l15) * 64 + ((((ks << 2) | lk) ^ axor) << 3));
        asm volatile("s_waitcnt lgkmcnt(0)" ::: "memory");
        __builtin_amdgcn_sched_barrier(0);
        asm volatile("s_barrier" ::: "memory");     // all waves done reading buf[cur]
        __builtin_amdgcn_sched_barrier(0);
        if (t + 2 < nt) stage(t + 2, cur);          // overwrite drained buffer under MFMA
        __builtin_amdgcn_sched_barrier(0);
        __builtin_amdgcn_s_setprio(1);
#pragma unroll
        for (int mi = 0; mi < 4; ++mi)
#pragma unroll
            for (int ni = 0; ni < 6; ++ni) {
                acc[mi][ni] = __builtin_amdgcn_mfma_f32_16x16x32_bf16(af[mi][0], bf[ni][0], acc[mi][ni], 0, 0, 0);
                acc[mi][ni] = __builtin_amdgcn_mfma_f32_16x16x32_bf16(af[mi][1], bf[ni][1], acc[mi][ni], 0, 0, 0);
            }
        __builtin_amdgcn_s_setprio(0);
        __builtin_amdgcn_sched_barrier(0);
    }

#pragma unroll
    for (int mi = 0; mi < 4; ++mi)
#pragma unroll
        for (int ni = 0; ni < 6; ++ni)
#pragma unroll
            for (int jj = 0; jj < 4; ++jj) {
                const int r = m_base + wr * 64 + mi * 16 + 4 * lk + jj;
                const int n = n_base + wc * 96 + ni * 16 + l15;
                float v = acc[mi][ni][jj];
                if (p.act) v = fast_tanh(v);
                if (p.outF) p.outF[(size_t)r * p.ldoF + n] = v;
                if (p.outB) p.outB[(size_t)r * p.ldoB + n] = f2b(v);
            }
}

// ---------------- small LDS-staged GEMM (m97 2-phase) ----------------

struct GemmP {
    const ushort* A;
    const ushort* Wt;
    int Ktot;
    int lda;
    ushort* outB;
    int ldoB;
    int outB_halo;      // row' = r + 4*(r>>11) + 2
    float* outF;
    int ldoF;
    int act;
};

template<int BM, int BN>
__global__ __launch_bounds__(256) void gemm_lds(GemmP p) {
    constexpr int MF = BM / 32;
    constexpr int NF = BN / 32;
    __shared__ __align__(16) ushort As[BM * 64];
    __shared__ __align__(16) ushort Bs[BN * 64];
    const int tid = threadIdx.x;
    const int w = tid >> 6, lane = tid & 63;
    const int l15 = lane & 15, lk = lane >> 4;
    const int m_base = blockIdx.x * BM;
    const int n_base = blockIdx.y * BN;
    const int wr = w >> 1, wc = w & 1;
    f32x4 acc[MF][NF] = {};
    const int srow = lane >> 3;
    const int scol = (lane & 7) * 8;
    const int nk = p.Ktot >> 6;

    for (int kt = 0; kt < nk; ++kt) {
        const int kk = kt << 6;
#pragma unroll
        for (int q = 0; q < BM / 32; ++q) {
            const int r = w * (BM / 4) + q * 8;
            gload16(p.A + (size_t)(m_base + r + srow) * p.lda + kk + scol, As + r * 64);
        }
#pragma unroll
        for (int q = 0; q < BN / 32; ++q) {
            const int r = w * (BN / 4) + q * 8;
            gload16(p.Wt + (size_t)(n_base + r + srow) * p.Ktot + kk + scol, Bs + r * 64);
        }
        __syncthreads();
#pragma unroll
        for (int ks = 0; ks < 2; ++ks) {
            short8 af[MF], bfr[NF];
#pragma unroll
            for (int i = 0; i < MF; ++i)
                af[i] = *(const short8*)(As + (wr * (BM / 2) + i * 16 + l15) * 64 + ks * 32 + 8 * lk);
#pragma unroll
            for (int j = 0; j < NF; ++j)
                bfr[j] = *(const short8*)(Bs + (wc * (BN / 2) + j * 16 + l15) * 64 + ks * 32 + 8 * lk);
#pragma unroll
            for (int i = 0; i < MF; ++i)
#pragma unroll
                for (int j = 0; j < NF; ++j)
                    acc[i][j] = __builtin_amdgcn_mfma_f32_16x16x32_bf16(af[i], bfr[j], acc[i][j], 0, 0, 0);
        }
        __syncthreads();
    }

    const int bb4 = ((m_base >> 11) << 2) + 2;
#pragma unroll
    for (int i = 0; i < MF; ++i)
#pragma unroll
        for (int j = 0; j < NF; ++j)
#pragma unroll
            for (int jj = 0; jj < 4; ++jj) {
                const int r = m_base + wr * (BM / 2) + i * 16 + 4 * lk + jj;
                const int n = n_base + wc * (BN / 2) + j * 16 + l15;
                float v = acc[i][j][jj];
                if (p.act) v = fast_tanh(v);
                if (p.outF) p.outF[(size_t)r * p.ldoF + n] = v;
                if (p.outB) {
                    const int rr = p.outB_halo ? (r + bb4) : r;
                    p.outB[(size_t)rr * p.ldoB + n] = f2b(v);
                }
            }
}

// ---------------- LayerNorm(conv_out + residual) -> bf16 ----------------

__global__ __launch_bounds__(192) void k_ln(const ushort* __restrict__ conv,
                                            const float* __restrict__ rep,
                                            const float* __restrict__ gw,
                                            const float* __restrict__ bw,
                                            ushort* __restrict__ out) {
    const int row = blockIdx.x;
    const int tid = threadIdx.x;
    const int h = tid * 4;
    const ushort4 cv = *(const ushort4*)(conv + (size_t)row * H_ + h);
    const float4  rv = *(const float4*)(rep + (size_t)row * H_ + h);
    float v[4] = { b2f(cv.x) + rv.x, b2f(cv.y) + rv.y, b2f(cv.z) + rv.z, b2f(cv.w) + rv.w };
    float s1 = v[0] + v[1] + v[2] + v[3];
    float s2 = v[0]*v[0] + v[1]*v[1] + v[2]*v[2] + v[3]*v[3];
#pragma unroll
    for (int off = 32; off; off >>= 1) { s1 += __shfl_xor(s1, off); s2 += __shfl_xor(s2, off); }
    __shared__ float sh[6];
    const int wid = tid >> 6, lane = tid & 63;
    if (lane == 0) { sh[wid] = s1; sh[3 + wid] = s2; }
    __syncthreads();
    s1 = sh[0] + sh[1] + sh[2];
    s2 = sh[3] + sh[4] + sh[5];
    const float mu  = s1 * (1.f / H_);
    const float var = s2 * (1.f / H_) - mu * mu;
    const float rs  = rsqrtf(var + 1e-5f);
    const float4 gv = *(const float4*)(gw + h);
    const float4 bv = *(const float4*)(bw + h);
    ushort4 o;
    o.x = f2b((v[0] - mu) * rs * gv.x + bv.x);
    o.y = f2b((v[1] - mu) * rs * gv.y + bv.y);
    o.z = f2b((v[2] - mu) * rs * gv.z + bv.z);
    o.w = f2b((v[3] - mu) * rs * gv.w + bv.w);
    *(ushort4*)(out + (size_t)row * H_ + h) = o;
}

// ---------------- row-normalize location -> bf16 ----------------

__global__ __launch_bounds__(256) void k_normed(const float* __restrict__ loc, ushort* __restrict__ out) {
    const int wid = threadIdx.x >> 6, lane = threadIdx.x & 63;
    const int row = blockIdx.x * 4 + wid;
    const float* lp = loc + (size_t)row * K_;
    const float x0 = lp[lane], x1 = lp[lane + 64];
    float ss = x0 * x0 + x1 * x1;
#pragma unroll
    for (int off = 32; off; off >>= 1) ss += __shfl_xor(ss, off);
    const float sc = 1.f / fmaxf(sqrtf(ss), 1e-8f);
    ushort* op = out + (size_t)row * K_;
    op[lane] = f2b(x0 * sc);
    op[lane + 64] = f2b(x1 * sc);
}

// ---------------- banded cosine-sim + tags (fused; band-skip for compute) --------------

__global__ __launch_bounds__(256) void k_simtags(const ushort* __restrict__ normed,
                                                 const float* __restrict__ mask,
                                                 const int* __restrict__ Lp,
                                                 float* __restrict__ dis,
                                                 float* __restrict__ tags) {
    const int wid = threadIdx.x >> 6, lane = threadIdx.x & 63;
    const int l15 = lane & 15, lk = lane >> 4;
    const int b   = blockIdx.z;
    const int i0b = blockIdx.x * 64;
    const int i0  = i0b + wid * 16;
    const int j0  = blockIdx.y * 64;
    const int L   = *Lp;
    f32x4 acc[4] = {};
    if ((j0 + 63 >= i0b + 1) && (j0 <= i0b + 63 + L)) {
        const ushort* nb = normed + (size_t)b * S_ * K_;
#pragma unroll
        for (int kt = 0; kt < 4; ++kt) {
            const int kk = kt * 32;
            const short8 a = *(const short8*)(nb + (size_t)(i0 + l15) * K_ + kk + 8 * lk);
#pragma unroll
            for (int j = 0; j < 4; ++j) {
                const short8 bfr = *(const short8*)(nb + (size_t)(j0 + j * 16 + l15) * K_ + kk + 8 * lk);
                acc[j] = __builtin_amdgcn_mfma_f32_16x16x32_bf16(a, bfr, acc[j], 0, 0, 0);
            }
        }
    }
    const float* mb = mask + b * S_;
    float* dp = dis  + (size_t)b * S_ * S_;
    float* tp = tags + (size_t)b * S_ * S_;
#pragma unroll
    for (int j = 0; j < 4; ++j) {
#pragma unroll
        for (int jj = 0; jj < 4; ++jj) {
            const int i  = i0 + 4 * lk + jj;
            const int jc = j0 + j * 16 + l15;
            const int d  = jc - i;
            const bool band = (d >= 1 && d <= L);
            dp[(size_t)i * S_ + jc] = band ? acc[j][jj] : 0.f;
            tp[(size_t)i * S_ + jc] = band ? mb[i] * mb[jc] : 0.f;
        }
    }
}

// ---------------- host launch ----------------

extern "C" void kernel_launch(void* const* d_in, const int* in_sizes, int n_in,
                              void* d_out, int out_size, void* d_ws, size_t ws_size,
                              hipStream_t stream) {
    const float* rep  = (const float*)d_in[0];
    const float* mask = (const float*)d_in[1];
    const float* ew1  = (const float*)d_in[2];
    const float* ew3  = (const float*)d_in[3];
    const float* ew5  = (const float*)d_in[4];
    const float* lng  = (const float*)d_in[5];
    const float* lnb  = (const float*)d_in[6];
    const float* elin = (const float*)d_in[7];
    const float* etr  = (const float*)d_in[8];
    const float* dtr  = (const float*)d_in[9];
    const float* dw1  = (const float*)d_in[10];
    const float* dw3  = (const float*)d_in[11];
    const float* dw5  = (const float*)d_in[12];
    const float* dlin = (const float*)d_in[13];
    const float* olin = (const float*)d_in[14];

    float* out_loc = (float*)d_out;
    float* out_dis = out_loc + (size_t)B_ * S_ * K_;
    float* out_tag = out_dis + (size_t)B_ * S_ * S_;
    float* out_dec = out_tag + (size_t)B_ * S_ * S_;

    char* ws = (char*)d_ws;
    size_t off = 0;
    auto alloc = [&](size_t bytes) -> char* {
        char* p = ws + off;
        off += (bytes + 255) & ~(size_t)255;
        return p;
    };
    int*    Lp    = (int*)alloc(256);
    ushort* Xh    = (ushort*)alloc((size_t)B_ * SH_ * H_ * 2);   // halo'd rep
    ushort* bufLh = (ushort*)alloc((size_t)B_ * SH_ * K_ * 2);   // halo'd location
    ushort* wte1  = (ushort*)alloc((size_t)C_ * 768 * 2);
    ushort* wte3  = (ushort*)alloc((size_t)C_ * 2304 * 2);
    ushort* wte5  = (ushort*)alloc((size_t)C_ * 3840 * 2);
    ushort* wtd1  = (ushort*)alloc((size_t)C_ * 768 * 2);
    ushort* wtd3  = (ushort*)alloc((size_t)C_ * 2304 * 2);
    ushort* wtd5  = (ushort*)alloc((size_t)C_ * 3840 * 2);
    ushort* welin = (ushort*)alloc((size_t)H_ * H_ * 2);
    ushort* wetr  = (ushort*)alloc((size_t)K_ * H_ * 2);
    ushort* dtrT  = (ushort*)alloc((size_t)K_ * H_ * 2);         // dec_tr^T [128][768]
    ushort* wdlin = (ushort*)alloc((size_t)H_ * H_ * 2);
    ushort* wolin = (ushort*)alloc((size_t)H_ * H_ * 2);
    ushort* wc1   = (ushort*)alloc((size_t)C_ * 128 * 2);        // composite [256][1*128]
    ushort* wc3   = (ushort*)alloc((size_t)C_ * 384 * 2);        // [256][3*128]
    ushort* wc5   = (ushort*)alloc((size_t)C_ * 640 * 2);        // [256][5*128]
    ushort* bufB  = (ushort*)alloc((size_t)MTOK * H_ * 2);
    ushort* bufC  = (ushort*)alloc((size_t)MTOK * H_ * 2);
    ushort* bufD  = (ushort*)alloc((size_t)MTOK * H_ * 2);
    ushort* bufN  = (ushort*)alloc((size_t)MTOK * K_ * 2);
    if (ws_size < off) return;

    // 1. max_act_len + bufLh halo zeroing + halo'd bf16 rep
    k_maxlen<<<1, 512, 0, stream>>>(mask, Lp, bufLh);
    k_build_xh<<<2048, 256, 0, stream>>>(rep, Xh);

    // 2. all weight conversions, one launch
    CvtAll ca;
    ca.e[0]  = { ew1,  wte1, 768 * C_,  768,  C_ };
    ca.e[1]  = { ew3,  wte3, 2304 * C_, 2304, C_ };
    ca.e[2]  = { ew5,  wte5, 3840 * C_, 3840, C_ };
    ca.e[3]  = { dw1,  wtd1, 768 * C_,  768,  C_ };
    ca.e[4]  = { dw3,  wtd3, 2304 * C_, 2304, C_ };
    ca.e[5]  = { dw5,  wtd5, 3840 * C_, 3840, C_ };
    ca.e[6]  = { elin, welin, H_ * H_, 0, 0 };
    ca.e[7]  = { etr,  wetr,  K_ * H_, 0, 0 };
    ca.e[8]  = { dlin, wdlin, H_ * H_, 0, 0 };
    ca.e[9]  = { olin, wolin, H_ * H_, 0, 0 };
    ca.e[10] = { dtr,  dtrT,  K_ * H_, 768, K_ };   // dtrT[j][h] = dtr[h][j]
    k_cvt_all<<<dim3(256, 11), 256, 0, stream>>>(ca);

    // 3. composite decoder conv weights: w'[t] = dec_tr^T @ w[t]  (transposed out)
    {
        CompP cp; cp.dtrT = dtrT;
        cp.e[0] = { wtd1, 768,  0,        wc1, 128, 0 };
        for (int t = 0; t < 3; ++t) cp.e[1 + t] = { wtd3, 2304, t * 768, wc3, 384, t * 128 };
        for (int t = 0; t < 5; ++t) cp.e[4 + t] = { wtd5, 3840, t * 768, wc5, 640, t * 128 };
        k_compw<<<dim3(2, 9), 256, 0, stream>>>(cp);
    }

    // 4. encoder convs (fused 3 branches, k=5 first) -> bufB
    {
        G3P p{}; p.A = Xh; p.W0 = wte1; p.W1 = wte3; p.W2 = wte5;
        p.lda = H_; p.outB = bufB; p.ldoB = H_; p.nMtiles = MTOK / 128;
        g3<false><<<3 * (MTOK / 128), 512, 0, stream>>>(p);
    }
    // 5. LN(conv + rep) -> bufC
    k_ln<<<MTOK, 192, 0, stream>>>(bufB, rep, lng, lnb, bufC);
    // 6. h2 = tanh(h_ln @ enc_lin^T) -> bufD
    {
        G4P p{}; p.A = bufC; p.W = welin; p.Ktot = H_; p.lda = H_;
        p.outB = bufD; p.ldoB = H_; p.act = 1;
        g4<<<dim3(MTOK / 128, H_ / 192), 256, 0, stream>>>(p);
    }
    // 7. location = h2 @ enc_tr^T -> out_loc (f32) + bufLh (bf16, halo'd)
    {
        GemmP p{}; p.A = bufD; p.lda = H_; p.Wt = wetr; p.Ktot = H_;
        p.outF = out_loc; p.ldoF = K_; p.outB = bufLh; p.ldoB = K_; p.outB_halo = 1;
        gemm_lds<64, 128><<<dim3(MTOK / 64, 1), 256, 0, stream>>>(p);
    }
    // 8. normed -> bufN
    k_normed<<<MTOK / 4, 256, 0, stream>>>(out_loc, bufN);
    // 9. decoder convs on location directly (composite weights) -> bufB
    {
        G3P p{}; p.A = bufLh; p.W0 = wc1; p.W1 = wc3; p.W2 = wc5;
        p.lda = K_; p.outB = bufB; p.ldoB = H_; p.nMtiles = MTOK / 128;
        g3<true><<<3 * (MTOK / 128), 512, 0, stream>>>(p);
    }
    // 10. d2 = tanh(d1 @ dec_lin^T) -> bufC
    {
        G4P p{}; p.A = bufB; p.W = wdlin; p.Ktot = H_; p.lda = H_;
        p.outB = bufC; p.ldoB = H_; p.act = 1;
        g4<<<dim3(MTOK / 128, H_ / 192), 256, 0, stream>>>(p);
    }
    // 11. decode_out = d2 @ out_lin^T -> out_dec (f32)
    {
        G4P p{}; p.A = bufC; p.W = wolin; p.Ktot = H_; p.lda = H_;
        p.outF = out_dec; p.ldoF = H_;
        g4<<<dim3(MTOK / 128, H_ / 192), 256, 0, stream>>>(p);
    }
    // 12. banded cosine sim + tags -> out_dis, out_tag
    k_simtags<<<dim3(S_ / 64, S_ / 64, B_), 256, 0, stream>>>(bufN, mask, Lp, out_dis, out_tag);
}